// Round 6
// baseline (311.843 us; speedup 1.0000x reference)
//
#include <hip/hip_runtime.h>
#include <hip/hip_bf16.h>

typedef __attribute__((ext_vector_type(8))) short short8;
typedef __attribute__((ext_vector_type(4))) float f32x4;
typedef __attribute__((ext_vector_type(4))) float float4v;
typedef __attribute__((ext_vector_type(8))) unsigned short ushort8;

// RNE float -> bf16 payload
__device__ __forceinline__ unsigned short f2bf(float f) {
    union { float f; unsigned u; } x; x.f = f;
    unsigned r = x.u + 0x7FFFu + ((x.u >> 16) & 1u);
    return (unsigned short)(r >> 16);
}

// C[k][n] = s(k) * cos(pi * k * (2n+1) / (2N)), N = 512, ortho norm.
__global__ __launch_bounds__(256) void make_dct_mat(unsigned short* __restrict__ Cm) {
    int idx = blockIdx.x * 256 + threadIdx.x;     // 0 .. 512*512-1
    int k = idx >> 9;
    int n = idx & 511;
    int m = (k * (2 * n + 1)) & 2047;             // mod 4N (N=512)
    float ang = (3.14159265358979323846f / 1024.0f) * (float)m;
    float s = (k == 0) ? 0.04419417382415922f : 0.0625f;  // 1/sqrt(512), sqrt(2/512)
    Cm[idx] = f2bf(s * cosf(ang));
}

#define GLD16(g, l) __builtin_amdgcn_global_load_lds( \
    (const __attribute__((address_space(1))) void*)(g), \
    (__attribute__((address_space(3))) void*)(l), 16, 0, 0)

#define SYNC_VM0()   asm volatile("s_waitcnt vmcnt(0)\n\ts_barrier" ::: "memory")
#define SYNC_FULL()  asm volatile("s_waitcnt vmcnt(0) lgkmcnt(0)\n\ts_barrier" ::: "memory")

// D[img] = A * B[img]^T   (512x512 row-major per image)
// 128x128 tile, BK=64 (two proven [128][32] swizzled sub-tiles), 4 waves (2x2),
// 2-slot double buffer, prefetch issued BEFORE compute, one barrier per K-step.
template <bool B_IS_F32, bool OUT_F32>
__device__ __forceinline__ void dct_gemm_body(
    const unsigned short* __restrict__ A,
    const void* __restrict__ Ball,
    void* __restrict__ Dall)
{
    // [slot][ksub][128*32]: each ksub sub-tile is the round-2 proven layout.
    __shared__ unsigned short As[2][2][128 * 32];   // 32 KB
    __shared__ unsigned short Bs[2][2][128 * 32];   // 32 KB

    // XCD-bijective swizzle: nwg = nimg*16, multiple of 8.
    int wg  = blockIdx.x;
    int cpx = gridDim.x >> 3;
    int swz = (wg & 7) * cpx + (wg >> 3);
    int img  = swz >> 4;
    int tile = swz & 15;
    int R0 = (tile >> 2) * 128;   // output rows (rows of C)
    int C0 = (tile & 3) * 128;    // output cols (rows of B)

    int t    = threadIdx.x;
    int lane = t & 63;
    int wid  = t >> 6;
    int wm   = wid >> 1;
    int wn   = wid & 1;

    f32x4 acc[4][4] = {};

    const size_t imgoff = (size_t)img * (512 * 512);

    // Proven round-2 swizzle: LDS (row, slotL) holds global slot slotL ^ ((row>>1)&3).
    // GLD16 dest linear t*16B -> (row = t>>2, slotL = t&3); source slot pre-XORed.
    const int aslot = ((t & 3) ^ ((t >> 3) & 3)) * 8;   // element offset in 32-col chunk
    const unsigned short* gA = A + (size_t)(R0 + (t >> 2)) * 512 + aslot;
    const unsigned short* gB16 = nullptr;
    const float* gBf = nullptr;
    if constexpr (B_IS_F32)
        gBf = (const float*)Ball + imgoff + (size_t)(C0 + (t >> 2)) * 512 + aslot;
    else
        gB16 = (const unsigned short*)Ball + imgoff + (size_t)(C0 + (t >> 2)) * 512 + aslot;

    auto stageA = [&](int sl, int kk) {
        #pragma unroll
        for (int ks = 0; ks < 2; ++ks) {
            GLD16(gA + kk + ks * 32,            &As[sl][ks][t * 8]);
            GLD16(gA + kk + ks * 32 + 64 * 512, &As[sl][ks][2048 + t * 8]);
        }
    };
    auto stageB16 = [&](int sl, int kk) {
        #pragma unroll
        for (int ks = 0; ks < 2; ++ks) {
            GLD16(gB16 + kk + ks * 32,            &Bs[sl][ks][t * 8]);
            GLD16(gB16 + kk + ks * 32 + 64 * 512, &Bs[sl][ks][2048 + t * 8]);
        }
    };

    // Stage-1 fp32 B: issue loads early (before compute), cvt + ds_write late.
    float4v breg[2][2][2];   // [ksub][row-half][lo/hi]
    auto loadBf32 = [&](int kk) {
        #pragma unroll
        for (int ks = 0; ks < 2; ++ks)
            #pragma unroll
            for (int h = 0; h < 2; ++h) {
                const float* p = gBf + kk + ks * 32 + (size_t)h * 64 * 512;
                breg[ks][h][0] = *(const float4v*)(p);
                breg[ks][h][1] = *(const float4v*)(p + 4);
            }
    };
    auto writeBf32 = [&](int sl) {
        #pragma unroll
        for (int ks = 0; ks < 2; ++ks)
            #pragma unroll
            for (int h = 0; h < 2; ++h) {
                union { ushort8 u8; __hip_bfloat162 h2[4]; } u;
                u.h2[0] = __float22bfloat162_rn(float2{breg[ks][h][0].x, breg[ks][h][0].y});
                u.h2[1] = __float22bfloat162_rn(float2{breg[ks][h][0].z, breg[ks][h][0].w});
                u.h2[2] = __float22bfloat162_rn(float2{breg[ks][h][1].x, breg[ks][h][1].y});
                u.h2[3] = __float22bfloat162_rn(float2{breg[ks][h][1].z, breg[ks][h][1].w});
                *(ushort8*)(&Bs[sl][ks][h * 2048 + t * 8]) = u.u8;   // linear: conflict-free
            }
    };

    auto compute = [&](int sl) {
        const int roff = ((lane >> 4) ^ ((lane >> 1) & 3)) * 8;   // proven read swizzle
        short8 av[4][2], bv[4][2];
        #pragma unroll
        for (int m = 0; m < 4; ++m)
            #pragma unroll
            for (int ks = 0; ks < 2; ++ks)
                av[m][ks] = *(const short8*)(&As[sl][ks][(wm * 64 + m * 16 + (lane & 15)) * 32 + roff]);
        #pragma unroll
        for (int n = 0; n < 4; ++n)
            #pragma unroll
            for (int ks = 0; ks < 2; ++ks)
                bv[n][ks] = *(const short8*)(&Bs[sl][ks][(wn * 64 + n * 16 + (lane & 15)) * 32 + roff]);
        __builtin_amdgcn_s_setprio(1);
        #pragma unroll
        for (int m = 0; m < 4; ++m)
            #pragma unroll
            for (int n = 0; n < 4; ++n)
                #pragma unroll
                for (int ks = 0; ks < 2; ++ks)
                    acc[m][n] = __builtin_amdgcn_mfma_f32_16x16x32_bf16(
                                    av[m][ks], bv[n][ks], acc[m][n], 0, 0, 0);
        __builtin_amdgcn_s_setprio(0);
    };

    // ---- prologue: stage tile 0 ----
    stageA(0, 0);
    if constexpr (B_IS_F32) {
        loadBf32(0);
        writeBf32(0);        // compiler inserts vmcnt wait for breg
        SYNC_FULL();
    } else {
        stageB16(0, 0);
        SYNC_VM0();
    }

    // ---- main loop: 8 K-steps, one barrier each, prefetch-before-compute ----
    #pragma unroll
    for (int kt = 0; kt < 8; ++kt) {
        const int sl = kt & 1;
        if (kt < 7) {
            stageA(sl ^ 1, (kt + 1) * 64);
            if constexpr (B_IS_F32) loadBf32((kt + 1) * 64);
            else                    stageB16(sl ^ 1, (kt + 1) * 64);
        }
        compute(sl);
        if (kt < 7) {
            if constexpr (B_IS_F32) {
                writeBf32(sl ^ 1);   // write-late: after compute, before barrier
                SYNC_FULL();
            } else {
                SYNC_VM0();
            }
        }
    }

    // ---- epilogue: C/D layout col = lane&15, row = (lane>>4)*4 + reg ----
    int r0 = R0 + wm * 64 + (lane >> 4) * 4;
    int c0 = C0 + wn * 64 + (lane & 15);
    if constexpr (OUT_F32) {
        float* D = (float*)Dall + imgoff;
        #pragma unroll
        for (int fm = 0; fm < 4; ++fm)
            #pragma unroll
            for (int fn = 0; fn < 4; ++fn)
                #pragma unroll
                for (int r = 0; r < 4; ++r)
                    D[(size_t)(r0 + fm * 16 + r) * 512 + c0 + fn * 16] = acc[fm][fn][r];
    } else {
        unsigned short* D = (unsigned short*)Dall + imgoff;
        #pragma unroll
        for (int fm = 0; fm < 4; ++fm)
            #pragma unroll
            for (int fn = 0; fn < 4; ++fn)
                #pragma unroll
                for (int r = 0; r < 4; ++r)
                    D[(size_t)(r0 + fm * 16 + r) * 512 + c0 + fn * 16] = f2bf(acc[fm][fn][r]);
    }
}

__global__ __launch_bounds__(256) void dct_gemm_s1(
    const unsigned short* __restrict__ A, const float* __restrict__ B,
    unsigned short* __restrict__ D) {
    dct_gemm_body<true, false>(A, B, D);
}

__global__ __launch_bounds__(256) void dct_gemm_s2(
    const unsigned short* __restrict__ A, const unsigned short* __restrict__ B,
    float* __restrict__ D) {
    dct_gemm_body<false, true>(A, B, D);
}

extern "C" void kernel_launch(void* const* d_in, const int* in_sizes, int n_in,
                              void* d_out, int out_size, void* d_ws, size_t ws_size,
                              hipStream_t stream) {
    const float* x = (const float*)d_in[0];
    float* out = (float*)d_out;

    // ws layout: [0, 512KB) = C matrix bf16; [1MB, 1MB+128MB) = intermediate T' bf16
    unsigned short* Cm = (unsigned short*)d_ws;
    unsigned short* Tm = (unsigned short*)((char*)d_ws + (1 << 20));

    int nimg = in_sizes[0] / (512 * 512);   // 256

    make_dct_mat<<<dim3(1024), dim3(256), 0, stream>>>(Cm);
    // Stage 1: T'[b] = C * X[b]^T   (B = fp32 -> cvt in regs -> bf16 LDS, out = bf16)
    dct_gemm_s1<<<dim3(nimg * 16), dim3(256), 0, stream>>>(Cm, x, Tm);
    // Stage 2: Y[b] = C * T'[b]^T = C X C^T  (B = bf16 via global_load_lds, out = fp32)
    dct_gemm_s2<<<dim3(nimg * 16), dim3(256), 0, stream>>>(Cm, Tm, out);
}

// Round 7
// 310.825 us; speedup vs baseline: 1.0033x; 1.0033x over previous
//
#include <hip/hip_runtime.h>
#include <hip/hip_bf16.h>

typedef __attribute__((ext_vector_type(8))) short short8;
typedef __attribute__((ext_vector_type(4))) float f32x4;
typedef __attribute__((ext_vector_type(4))) float float4v;
typedef __attribute__((ext_vector_type(8))) unsigned short ushort8;

// RNE float -> bf16 payload
__device__ __forceinline__ unsigned short f2bf(float f) {
    union { float f; unsigned u; } x; x.f = f;
    unsigned r = x.u + 0x7FFFu + ((x.u >> 16) & 1u);
    return (unsigned short)(r >> 16);
}

// C[k][n] = s(k) * cos(pi * k * (2n+1) / (2N)), N = 512, ortho norm.
__global__ __launch_bounds__(256) void make_dct_mat(unsigned short* __restrict__ Cm) {
    int idx = blockIdx.x * 256 + threadIdx.x;     // 0 .. 512*512-1
    int k = idx >> 9;
    int n = idx & 511;
    int m = (k * (2 * n + 1)) & 2047;             // mod 4N (N=512)
    float ang = (3.14159265358979323846f / 1024.0f) * (float)m;
    float s = (k == 0) ? 0.04419417382415922f : 0.0625f;  // 1/sqrt(512), sqrt(2/512)
    Cm[idx] = f2bf(s * cosf(ang));
}

#define GLD16(g, l) __builtin_amdgcn_global_load_lds( \
    (const __attribute__((address_space(1))) void*)(g), \
    (__attribute__((address_space(3))) void*)(l), 16, 0, 0)

#define SYNC_VM0()   asm volatile("s_waitcnt vmcnt(0)\n\ts_barrier" ::: "memory")
#define SYNC_FULL()  asm volatile("s_waitcnt vmcnt(0) lgkmcnt(0)\n\ts_barrier" ::: "memory")

// D[img] = A * B[img]^T   (512x512 row-major per image)
// 128x128 tile, BK=64 (two proven [128][32] swizzled sub-tiles), 4 waves (2x2),
// 2-slot double buffer, prefetch issued BEFORE compute, one barrier per K-step.
template <bool B_IS_F32, bool OUT_F32>
__device__ __forceinline__ void dct_gemm_body(
    const unsigned short* __restrict__ A,
    const void* __restrict__ Ball,
    void* __restrict__ Dall)
{
    // [slot][ksub][128*32]: each ksub sub-tile is the round-2 proven layout.
    __shared__ unsigned short As[2][2][128 * 32];   // 32 KB
    __shared__ unsigned short Bs[2][2][128 * 32];   // 32 KB

    // XCD-bijective swizzle: nwg = nimg*16, multiple of 8.
    int wg  = blockIdx.x;
    int cpx = gridDim.x >> 3;
    int swz = (wg & 7) * cpx + (wg >> 3);
    int img  = swz >> 4;
    int tile = swz & 15;
    int R0 = (tile >> 2) * 128;   // output rows (rows of C)
    int C0 = (tile & 3) * 128;    // output cols (rows of B)

    int t    = threadIdx.x;
    int lane = t & 63;
    int wid  = t >> 6;
    int wm   = wid >> 1;
    int wn   = wid & 1;

    f32x4 acc[4][4] = {};

    const size_t imgoff = (size_t)img * (512 * 512);

    // Proven round-2 swizzle: LDS (row, slotL) holds global slot slotL ^ ((row>>1)&3).
    // GLD16 dest linear t*16B -> (row = t>>2, slotL = t&3); source slot pre-XORed.
    const int aslot = ((t & 3) ^ ((t >> 3) & 3)) * 8;   // element offset in 32-col chunk
    const unsigned short* gA = A + (size_t)(R0 + (t >> 2)) * 512 + aslot;
    const unsigned short* gB16 = nullptr;
    const float* gBf = nullptr;
    if constexpr (B_IS_F32)
        gBf = (const float*)Ball + imgoff + (size_t)(C0 + (t >> 2)) * 512 + aslot;
    else
        gB16 = (const unsigned short*)Ball + imgoff + (size_t)(C0 + (t >> 2)) * 512 + aslot;

    auto stageA = [&](int sl, int kk) {
        #pragma unroll
        for (int ks = 0; ks < 2; ++ks) {
            GLD16(gA + kk + ks * 32,            &As[sl][ks][t * 8]);
            GLD16(gA + kk + ks * 32 + 64 * 512, &As[sl][ks][2048 + t * 8]);
        }
    };
    auto stageB16 = [&](int sl, int kk) {
        #pragma unroll
        for (int ks = 0; ks < 2; ++ks) {
            GLD16(gB16 + kk + ks * 32,            &Bs[sl][ks][t * 8]);
            GLD16(gB16 + kk + ks * 32 + 64 * 512, &Bs[sl][ks][2048 + t * 8]);
        }
    };

    // Stage-1 fp32 B: issue loads early (before compute), cvt + ds_write late.
    float4v breg[2][2][2];   // [ksub][row-half][lo/hi]
    auto loadBf32 = [&](int kk) {
        #pragma unroll
        for (int ks = 0; ks < 2; ++ks)
            #pragma unroll
            for (int h = 0; h < 2; ++h) {
                const float* p = gBf + kk + ks * 32 + (size_t)h * 64 * 512;
                breg[ks][h][0] = *(const float4v*)(p);
                breg[ks][h][1] = *(const float4v*)(p + 4);
            }
    };
    auto writeBf32 = [&](int sl) {
        #pragma unroll
        for (int ks = 0; ks < 2; ++ks)
            #pragma unroll
            for (int h = 0; h < 2; ++h) {
                union { ushort8 u8; __hip_bfloat162 h2[4]; } u;
                u.h2[0] = __float22bfloat162_rn(float2{breg[ks][h][0].x, breg[ks][h][0].y});
                u.h2[1] = __float22bfloat162_rn(float2{breg[ks][h][0].z, breg[ks][h][0].w});
                u.h2[2] = __float22bfloat162_rn(float2{breg[ks][h][1].x, breg[ks][h][1].y});
                u.h2[3] = __float22bfloat162_rn(float2{breg[ks][h][1].z, breg[ks][h][1].w});
                *(ushort8*)(&Bs[sl][ks][h * 2048 + t * 8]) = u.u8;   // linear: conflict-free
            }
    };

    auto compute = [&](int sl) {
        const int roff = ((lane >> 4) ^ ((lane >> 1) & 3)) * 8;   // proven read swizzle
        short8 av[4][2], bv[4][2];
        #pragma unroll
        for (int m = 0; m < 4; ++m)
            #pragma unroll
            for (int ks = 0; ks < 2; ++ks)
                av[m][ks] = *(const short8*)(&As[sl][ks][(wm * 64 + m * 16 + (lane & 15)) * 32 + roff]);
        #pragma unroll
        for (int n = 0; n < 4; ++n)
            #pragma unroll
            for (int ks = 0; ks < 2; ++ks)
                bv[n][ks] = *(const short8*)(&Bs[sl][ks][(wn * 64 + n * 16 + (lane & 15)) * 32 + roff]);
        __builtin_amdgcn_s_setprio(1);
        #pragma unroll
        for (int m = 0; m < 4; ++m)
            #pragma unroll
            for (int n = 0; n < 4; ++n)
                #pragma unroll
                for (int ks = 0; ks < 2; ++ks)
                    acc[m][n] = __builtin_amdgcn_mfma_f32_16x16x32_bf16(
                                    av[m][ks], bv[n][ks], acc[m][n], 0, 0, 0);
        __builtin_amdgcn_s_setprio(0);
    };

    // ---- prologue: stage tile 0 ----
    stageA(0, 0);
    if constexpr (B_IS_F32) {
        loadBf32(0);
        writeBf32(0);        // compiler inserts vmcnt wait for breg
        SYNC_FULL();
    } else {
        stageB16(0, 0);
        SYNC_VM0();
    }

    // ---- main loop: 8 K-steps, one barrier each, prefetch-before-compute ----
    #pragma unroll
    for (int kt = 0; kt < 8; ++kt) {
        const int sl = kt & 1;
        if (kt < 7) {
            stageA(sl ^ 1, (kt + 1) * 64);
            if constexpr (B_IS_F32) loadBf32((kt + 1) * 64);
            else                    stageB16(sl ^ 1, (kt + 1) * 64);
        }
        compute(sl);
        if (kt < 7) {
            if constexpr (B_IS_F32) {
                writeBf32(sl ^ 1);   // write-late: after compute, before barrier
                SYNC_FULL();
            } else {
                SYNC_VM0();
            }
        }
    }

    // ---- epilogue: C/D layout col = lane&15, row = (lane>>4)*4 + reg ----
    int r0 = R0 + wm * 64 + (lane >> 4) * 4;
    int c0 = C0 + wn * 64 + (lane & 15);
    if constexpr (OUT_F32) {
        float* D = (float*)Dall + imgoff;
        #pragma unroll
        for (int fm = 0; fm < 4; ++fm)
            #pragma unroll
            for (int fn = 0; fn < 4; ++fn)
                #pragma unroll
                for (int r = 0; r < 4; ++r)
                    D[(size_t)(r0 + fm * 16 + r) * 512 + c0 + fn * 16] = acc[fm][fn][r];
    } else {
        unsigned short* D = (unsigned short*)Dall + imgoff;
        #pragma unroll
        for (int fm = 0; fm < 4; ++fm)
            #pragma unroll
            for (int fn = 0; fn < 4; ++fn)
                #pragma unroll
                for (int r = 0; r < 4; ++r)
                    D[(size_t)(r0 + fm * 16 + r) * 512 + c0 + fn * 16] = f2bf(acc[fm][fn][r]);
    }
}

__global__ __launch_bounds__(256) void dct_gemm_s1(
    const unsigned short* __restrict__ A, const float* __restrict__ B,
    unsigned short* __restrict__ D) {
    dct_gemm_body<true, false>(A, B, D);
}

__global__ __launch_bounds__(256) void dct_gemm_s2(
    const unsigned short* __restrict__ A, const unsigned short* __restrict__ B,
    float* __restrict__ D) {
    dct_gemm_body<false, true>(A, B, D);
}

extern "C" void kernel_launch(void* const* d_in, const int* in_sizes, int n_in,
                              void* d_out, int out_size, void* d_ws, size_t ws_size,
                              hipStream_t stream) {
    const float* x = (const float*)d_in[0];
    float* out = (float*)d_out;

    // ws layout: [0, 512KB) = C matrix bf16; [1MB, 1MB+128MB) = intermediate T' bf16
    unsigned short* Cm = (unsigned short*)d_ws;
    unsigned short* Tm = (unsigned short*)((char*)d_ws + (1 << 20));

    int nimg = in_sizes[0] / (512 * 512);   // 256

    make_dct_mat<<<dim3(1024), dim3(256), 0, stream>>>(Cm);
    // Stage 1: T'[b] = C * X[b]^T   (B = fp32 -> cvt in regs -> bf16 LDS, out = bf16)
    dct_gemm_s1<<<dim3(nimg * 16), dim3(256), 0, stream>>>(Cm, x, Tm);
    // Stage 2: Y[b] = C * T'[b]^T = C X C^T  (B = bf16 via global_load_lds, out = fp32)
    dct_gemm_s2<<<dim3(nimg * 16), dim3(256), 0, stream>>>(Cm, Tm, out);
}

// Round 8
// 260.866 us; speedup vs baseline: 1.1954x; 1.1915x over previous
//
#include <hip/hip_runtime.h>
#include <hip/hip_bf16.h>

typedef __attribute__((ext_vector_type(8))) short short8;
typedef __attribute__((ext_vector_type(4))) float f32x4;
typedef __attribute__((ext_vector_type(4))) float float4v;
typedef __attribute__((ext_vector_type(8))) unsigned short ushort8;

// RNE float -> bf16 payload
__device__ __forceinline__ unsigned short f2bf(float f) {
    union { float f; unsigned u; } x; x.f = f;
    unsigned r = x.u + 0x7FFFu + ((x.u >> 16) & 1u);
    return (unsigned short)(r >> 16);
}

// C[k][n] = s(k) * cos(pi * k * (2n+1) / (2N)), N = 512, ortho norm.
__global__ __launch_bounds__(256) void make_dct_mat(unsigned short* __restrict__ Cm) {
    int idx = blockIdx.x * 256 + threadIdx.x;     // 0 .. 512*512-1
    int k = idx >> 9;
    int n = idx & 511;
    int m = (k * (2 * n + 1)) & 2047;             // mod 4N (N=512)
    float ang = (3.14159265358979323846f / 1024.0f) * (float)m;
    float s = (k == 0) ? 0.04419417382415922f : 0.0625f;  // 1/sqrt(512), sqrt(2/512)
    Cm[idx] = f2bf(s * cosf(ang));
}

#define GLD16(g, l) __builtin_amdgcn_global_load_lds( \
    (const __attribute__((address_space(1))) void*)(g), \
    (__attribute__((address_space(3))) void*)(l), 16, 0, 0)

// D[img] = A * B[img]^T  (512x512 row-major per image).
// Block tile: BM=512 (ALL output rows; A = C matrix, L2-hot) x BN=128.
// -> B panel (X or T') is read from memory EXACTLY ONCE (was 4x).
// 8 waves (4M x 2N), wave tile 128x64, BK=32, 16 K-steps.
// 3-slot LDS ring, prefetch distance 2, counted vmcnt (never 0 mid-loop).
// LDS sub-tiles use the round-2/7 layout measured at ZERO bank conflicts.
template <bool B_IS_F32, bool OUT_F32>
__device__ __forceinline__ void dct_gemm_body(
    const unsigned short* __restrict__ A,
    const void* __restrict__ Ball,
    void* __restrict__ Dall)
{
    // A slot: 4 msub x [128 rows][32 cols] bf16 = 32 KB. B slot: [128][32] = 8 KB.
    __shared__ unsigned short As[3][4][128 * 32];   // 96 KB
    __shared__ unsigned short Bs[3][128 * 32];      // 24 KB

    // XCD-bijective swizzle (1024 % 8 == 0).
    int wg  = blockIdx.x;
    int cpx = gridDim.x >> 3;
    int swz = (wg & 7) * cpx + (wg >> 3);
    int img = swz >> 2;
    int C0  = (swz & 3) * 128;    // output-column strip within image

    int t    = threadIdx.x;       // 0..511
    int lane = t & 63;
    int wid  = t >> 6;            // 0..7
    int wm   = wid >> 1;          // 0..3 -> rows [wm*128, +128)
    int wn   = wid & 1;           // 0..1 -> cols [C0 + wn*64, +64)

    f32x4 acc[8][4] = {};         // 128 VGPR accumulator

    const size_t imgoff = (size_t)img * (512 * 512);

    // Proven swizzle: LDS (row, slotL) holds global 16B-slot slotL ^ ((row>>1)&3).
    // GLD16 dest linear t*16B within an 8KB sub-tile -> (row = t>>2, slotL = t&3).
    const int aslotG = ((t & 3) ^ ((t >> 3) & 3)) * 8;   // element offset in 32-col chunk
    const unsigned short* gA = A + (size_t)(t >> 2) * 512 + aslotG;
    const unsigned short* gB16 = nullptr;
    const float* gBf = nullptr;
    if constexpr (B_IS_F32)
        gBf = (const float*)Ball + imgoff + (size_t)(C0 + (t >> 2)) * 512 + aslotG;
    else
        gB16 = (const unsigned short*)Ball + imgoff + (size_t)(C0 + (t >> 2)) * 512 + aslotG;

    auto stageA = [&](int sl, int kk) {             // 4 GLD16 / thread
        #pragma unroll
        for (int ms = 0; ms < 4; ++ms)
            GLD16(gA + (size_t)ms * 128 * 512 + kk, &As[sl][ms][t * 8]);
    };
    auto stageB16 = [&](int sl, int kk) {           // 1 GLD16 / thread
        GLD16(gB16 + kk, &Bs[sl][t * 8]);
    };

    // Stage-1 fp32 B: 2 x float4 loads -> regs (issue early), cvt+ds_write late.
    float4v br[2][2];
    auto loadBf32 = [&](int which, int kk) {        // 2 vmem loads / thread
        br[which][0] = *(const float4v*)(gBf + kk);
        br[which][1] = *(const float4v*)(gBf + kk + 4);
    };
    auto writeBf32 = [&](int sl, int which) {       // 1 ds_write_b128 / thread
        union { ushort8 u8; __hip_bfloat162 h2[4]; } u;
        u.h2[0] = __float22bfloat162_rn(float2{br[which][0].x, br[which][0].y});
        u.h2[1] = __float22bfloat162_rn(float2{br[which][0].z, br[which][0].w});
        u.h2[2] = __float22bfloat162_rn(float2{br[which][1].x, br[which][1].y});
        u.h2[3] = __float22bfloat162_rn(float2{br[which][1].z, br[which][1].w});
        *(ushort8*)(&Bs[sl][t * 8]) = u.u8;
    };

    auto compute = [&](int sl) {
        const int roff = ((lane >> 4) ^ ((lane >> 1) & 3)) * 8;   // proven read swizzle
        short8 av[8], bv[4];
        #pragma unroll
        for (int m = 0; m < 8; ++m)
            av[m] = *(const short8*)(&As[sl][wm][(m * 16 + (lane & 15)) * 32 + roff]);
        #pragma unroll
        for (int n = 0; n < 4; ++n)
            bv[n] = *(const short8*)(&Bs[sl][(wn * 64 + n * 16 + (lane & 15)) * 32 + roff]);
        __builtin_amdgcn_s_setprio(1);
        #pragma unroll
        for (int m = 0; m < 8; ++m)
            #pragma unroll
            for (int n = 0; n < 4; ++n)
                acc[m][n] = __builtin_amdgcn_mfma_f32_16x16x32_bf16(
                                av[m], bv[n], acc[m][n], 0, 0, 0);
        __builtin_amdgcn_s_setprio(0);
    };

    // ---- prologue: tiles 0,1 staged; tile-1 loads stay outstanding ----
    if constexpr (B_IS_F32) {
        loadBf32(0, 0);          // br0 <- tile0      [2 loads]
        stageA(0, 0);            //                   [4]
        stageA(1, 32);           //                   [4]
        loadBf32(1, 32);         // br1 <- tile1      [2]
        asm volatile("s_waitcnt vmcnt(6)" ::: "memory");   // retire br0 + A(0)
        writeBf32(0, 0);
        asm volatile("s_waitcnt lgkmcnt(0)\n\ts_barrier" ::: "memory");
    } else {
        stageA(0, 0);  stageB16(0, 0);     // tile0  [5]
        stageA(1, 32); stageB16(1, 32);    // tile1  [5]
        asm volatile("s_waitcnt vmcnt(5)\n\ts_barrier" ::: "memory");
    }

    // ---- main loop: 16 K-steps; slot kt%3; prefetch tile kt+2; counted vmcnt ----
    #pragma unroll
    for (int kt = 0; kt < 16; ++kt) {
        if (kt < 14) {
            stageA((kt + 2) % 3, (kt + 2) * 32);
            if constexpr (B_IS_F32) loadBf32(kt & 1, (kt + 2) * 32);
            else                    stageB16((kt + 2) % 3, (kt + 2) * 32);
        }
        compute(kt % 3);
        if (kt < 15) {
            if constexpr (B_IS_F32) {
                // retire tile(kt+1)'s A-GLD and breg loads; keep tile(kt+2)'s 6 in flight
                if (kt < 14) asm volatile("s_waitcnt vmcnt(6)" ::: "memory");
                else         asm volatile("s_waitcnt vmcnt(0)" ::: "memory");
                writeBf32((kt + 1) % 3, (kt + 1) & 1);
                asm volatile("s_waitcnt lgkmcnt(0)\n\ts_barrier" ::: "memory");
            } else {
                if (kt < 14) asm volatile("s_waitcnt vmcnt(5)\n\ts_barrier" ::: "memory");
                else         asm volatile("s_waitcnt vmcnt(0)\n\ts_barrier" ::: "memory");
            }
        }
    }

    // ---- epilogue: C/D layout col = lane&15, row = (lane>>4)*4 + reg ----
    int r0 = wm * 128 + (lane >> 4) * 4;
    int c0 = C0 + wn * 64 + (lane & 15);
    if constexpr (OUT_F32) {
        float* D = (float*)Dall + imgoff;
        #pragma unroll
        for (int m = 0; m < 8; ++m)
            #pragma unroll
            for (int n = 0; n < 4; ++n)
                #pragma unroll
                for (int r = 0; r < 4; ++r)
                    D[(size_t)(r0 + m * 16 + r) * 512 + c0 + n * 16] = acc[m][n][r];
    } else {
        unsigned short* D = (unsigned short*)Dall + imgoff;
        #pragma unroll
        for (int m = 0; m < 8; ++m)
            #pragma unroll
            for (int n = 0; n < 4; ++n)
                #pragma unroll
                for (int r = 0; r < 4; ++r)
                    D[(size_t)(r0 + m * 16 + r) * 512 + c0 + n * 16] = f2bf(acc[m][n][r]);
    }
}

__global__ __launch_bounds__(512) void dct_gemm_s1(
    const unsigned short* __restrict__ A, const float* __restrict__ B,
    unsigned short* __restrict__ D) {
    dct_gemm_body<true, false>(A, B, D);
}

__global__ __launch_bounds__(512) void dct_gemm_s2(
    const unsigned short* __restrict__ A, const unsigned short* __restrict__ B,
    float* __restrict__ D) {
    dct_gemm_body<false, true>(A, B, D);
}

extern "C" void kernel_launch(void* const* d_in, const int* in_sizes, int n_in,
                              void* d_out, int out_size, void* d_ws, size_t ws_size,
                              hipStream_t stream) {
    const float* x = (const float*)d_in[0];
    float* out = (float*)d_out;

    // ws layout: [0, 512KB) = C matrix bf16; [1MB, 1MB+128MB) = intermediate T' bf16
    unsigned short* Cm = (unsigned short*)d_ws;
    unsigned short* Tm = (unsigned short*)((char*)d_ws + (1 << 20));

    int nimg = in_sizes[0] / (512 * 512);   // 256

    make_dct_mat<<<dim3(1024), dim3(256), 0, stream>>>(Cm);
    // Stage 1: T'[b] = C * X[b]^T   (B = fp32 -> cvt in regs -> bf16 LDS, out = bf16)
    dct_gemm_s1<<<dim3(nimg * 4), dim3(512), 0, stream>>>(Cm, x, Tm);
    // Stage 2: Y[b] = C * T'[b]^T = C X C^T  (B = bf16 via global_load_lds, out = fp32)
    dct_gemm_s2<<<dim3(nimg * 4), dim3(512), 0, stream>>>(Cm, Tm, out);
}